// Round 4
// baseline (99.722 us; speedup 1.0000x reference)
//
#include <hip/hip_runtime.h>
#include <math.h>

#define EPS 1e-6f

constexpr int B_ = 32;
constexpr int T_ = 8192;
constexpr int F_ = 128;
constexpr int FG = F_ / 4;   // 32 float4 feature-groups per row

typedef float f32x4 __attribute__((ext_vector_type(4)));

// fast pow for strictly-positive base
__device__ __forceinline__ float fpow(float b, float e) {
    return exp2f(e * __log2f(b));
}

// -------- pass 1: per-chunk local sum with zero initial carry --------
// block = 256 threads = 8 chunk-slots x 32 feature-groups; each thread owns 4 features.
template<int NC>
__global__ __launch_bounds__(256) void pcen_pass1(
    const float4* __restrict__ x4,
    const float*  __restrict__ log_s,
    float4* __restrict__ S4)
{
    constexpr int L = T_ / NC;
    const int fg    = threadIdx.x & 31;
    const int slot  = threadIdx.x >> 5;              // 0..7
    const int cb    = blockIdx.x % (NC / 8);
    const int b     = blockIdx.x / (NC / 8);
    const int chunk = cb * 8 + slot;

    const float4 lsv = reinterpret_cast<const float4*>(log_s)[fg];
    const float s0 = expf(lsv.x), s1 = expf(lsv.y), s2 = expf(lsv.z), s3 = expf(lsv.w);
    const float a0 = 1.f - s0,   a1 = 1.f - s1,    a2 = 1.f - s2,    a3 = 1.f - s3;

    const float4* xp = x4 + ((size_t)b * T_ + (size_t)chunk * L) * FG + fg;

    float c0 = 0.f, c1 = 0.f, c2 = 0.f, c3 = 0.f;
    #pragma unroll 16
    for (int i = 0; i < L; ++i) {
        const float4 xv = xp[(size_t)i * FG];
        c0 = fmaf(a0, c0, s0 * xv.x);
        c1 = fmaf(a1, c1, s1 * xv.y);
        c2 = fmaf(a2, c2, s2 * xv.z);
        c3 = fmaf(a3, c3, s3 * xv.w);
    }
    S4[((size_t)b * NC + chunk) * FG + fg] = make_float4(c0, c1, c2, c3);
}

// -------- fused pass: in-register carry scan + recurrence + y --------
template<int NC>
__global__ __launch_bounds__(256) void pcen_fused(
    const float4* __restrict__ x4,
    const float4* __restrict__ state4,
    const float*  __restrict__ log_s,
    const float*  __restrict__ log_alpha,
    const float*  __restrict__ log_delta,
    const float*  __restrict__ log_r,
    const float4* __restrict__ S4,
    float4* __restrict__ y4,
    float4* __restrict__ new_state4)
{
    constexpr int L = T_ / NC;
    const int fg    = threadIdx.x & 31;
    const int slot  = threadIdx.x >> 5;
    const int cb    = blockIdx.x % (NC / 8);
    const int b     = blockIdx.x / (NC / 8);
    const int chunk = cb * 8 + slot;

    const float4 lsv = reinterpret_cast<const float4*>(log_s)[fg];
    const float s0 = expf(lsv.x), s1 = expf(lsv.y), s2 = expf(lsv.z), s3 = expf(lsv.w);
    const float a0 = 1.f - s0,   a1 = 1.f - s1,    a2 = 1.f - s2,    a3 = 1.f - s3;

    // aL = a^L for the chunk-combine
    const float aL0 = fpow(a0, (float)L);
    const float aL1 = fpow(a1, (float)L);
    const float aL2 = fpow(a2, (float)L);
    const float aL3 = fpow(a3, (float)L);

    // --- in-register prefix: carry into this chunk ---
    float4 c = state4[(size_t)b * FG + fg];
    for (int k = 0; k < chunk; ++k) {
        const float4 Sv = S4[((size_t)b * NC + k) * FG + fg];
        c.x = fmaf(aL0, c.x, Sv.x);
        c.y = fmaf(aL1, c.y, Sv.y);
        c.z = fmaf(aL2, c.z, Sv.z);
        c.w = fmaf(aL3, c.w, Sv.w);
    }

    // --- y parameters ---
    const float4 lav = reinterpret_cast<const float4*>(log_alpha)[fg];
    const float4 ldv = reinterpret_cast<const float4*>(log_delta)[fg];
    const float4 lrv = reinterpret_cast<const float4*>(log_r)[fg];
    const float na0 = -expf(lav.x), na1 = -expf(lav.y), na2 = -expf(lav.z), na3 = -expf(lav.w);
    const float d0 = expf(ldv.x), d1 = expf(ldv.y), d2 = expf(ldv.z), d3 = expf(ldv.w);
    const float r0 = expf(lrv.x), r1 = expf(lrv.y), r2 = expf(lrv.z), r3 = expf(lrv.w);
    const float dr0 = fpow(d0, r0), dr1 = fpow(d1, r1);
    const float dr2 = fpow(d2, r2), dr3 = fpow(d3, r3);

    const size_t base = ((size_t)b * T_ + (size_t)chunk * L) * FG + fg;
    const float4* xp = x4 + base;
    f32x4*        yp = reinterpret_cast<f32x4*>(y4) + base;

    #pragma unroll 4
    for (int i = 0; i < L; ++i) {
        const float4 xv = xp[(size_t)i * FG];

        c.x = fmaf(a0, c.x, s0 * xv.x);
        c.y = fmaf(a1, c.y, s1 * xv.y);
        c.z = fmaf(a2, c.z, s2 * xv.z);
        c.w = fmaf(a3, c.w, s3 * xv.w);

        // u = x * (EPS+E)^(-alpha);  y = (u + delta)^r - delta^r
        const float u0 = xv.x * exp2f(na0 * __log2f(EPS + c.x));
        const float u1 = xv.y * exp2f(na1 * __log2f(EPS + c.y));
        const float u2 = xv.z * exp2f(na2 * __log2f(EPS + c.z));
        const float u3 = xv.w * exp2f(na3 * __log2f(EPS + c.w));

        f32x4 yv;
        yv.x = exp2f(r0 * __log2f(u0 + d0)) - dr0;
        yv.y = exp2f(r1 * __log2f(u1 + d1)) - dr1;
        yv.z = exp2f(r2 * __log2f(u2 + d2)) - dr2;
        yv.w = exp2f(r3 * __log2f(u3 + d3)) - dr3;

        // non-temporal: don't let y evict x from L3
        __builtin_nontemporal_store(yv, &yp[(size_t)i * FG]);
    }

    // last chunk's final carry IS the final state (exact stepwise path)
    if (chunk == NC - 1) {
        float4 cs;
        cs.x = c.x; cs.y = c.y; cs.z = c.z; cs.w = c.w;
        new_state4[(size_t)b * FG + fg] = cs;
    }
}

template<int NC>
static void launch_all(const float* x, const float* state,
                       const float* log_s, const float* log_alpha,
                       const float* log_delta, const float* log_r,
                       float* y, float* new_state, float* ws, hipStream_t stream)
{
    const float4* x4      = (const float4*)x;
    const float4* state4  = (const float4*)state;
    float4* y4            = (float4*)y;
    float4* new_state4    = (float4*)new_state;
    float4* S4            = (float4*)ws;     // B*NC*FG float4

    dim3 blk(256);
    dim3 grid(B_ * (NC / 8));

    pcen_pass1<NC><<<grid, blk, 0, stream>>>(x4, log_s, S4);
    pcen_fused<NC><<<grid, blk, 0, stream>>>(x4, state4, log_s, log_alpha,
                                             log_delta, log_r, S4, y4, new_state4);
}

extern "C" void kernel_launch(void* const* d_in, const int* in_sizes, int n_in,
                              void* d_out, int out_size, void* d_ws, size_t ws_size,
                              hipStream_t stream)
{
    const float* x         = (const float*)d_in[0];
    const float* state     = (const float*)d_in[1];
    const float* log_s     = (const float*)d_in[2];
    const float* log_alpha = (const float*)d_in[3];
    const float* log_delta = (const float*)d_in[4];
    const float* log_r     = (const float*)d_in[5];

    float* y         = (float*)d_out;
    float* new_state = y + (size_t)B_ * T_ * F_;

    const size_t need128 = (size_t)B_ * 128 * F_ * sizeof(float);   // 2 MB
    if (ws_size >= need128) {
        launch_all<128>(x, state, log_s, log_alpha, log_delta, log_r,
                        y, new_state, (float*)d_ws, stream);
    } else {
        launch_all<64>(x, state, log_s, log_alpha, log_delta, log_r,
                       y, new_state, (float*)d_ws, stream);
    }
}

// Round 5
// 84.300 us; speedup vs baseline: 1.1829x; 1.1829x over previous
//
#include <hip/hip_runtime.h>
#include <math.h>

#define EPS 1e-6f

constexpr int B_ = 32;
constexpr int T_ = 8192;
constexpr int F_ = 128;
constexpr int FG = F_ / 4;   // 32 float4 feature-groups per row

// fast pow for strictly-positive base
__device__ __forceinline__ float fpow(float b, float e) {
    return exp2f(e * __log2f(b));
}

// -------- pass 1: per-chunk local sum with zero initial carry --------
// block = 256 threads = 8 chunk-slots x 32 feature-groups; each thread owns 4 features.
template<int NC>
__global__ __launch_bounds__(256) void pcen_pass1(
    const float4* __restrict__ x4,
    const float*  __restrict__ log_s,
    float4* __restrict__ S4)
{
    constexpr int L = T_ / NC;
    const int fg    = threadIdx.x & 31;
    const int slot  = threadIdx.x >> 5;              // 0..7
    const int cb    = blockIdx.x % (NC / 8);
    const int b     = blockIdx.x / (NC / 8);
    const int chunk = cb * 8 + slot;

    const float4 lsv = reinterpret_cast<const float4*>(log_s)[fg];
    const float s0 = expf(lsv.x), s1 = expf(lsv.y), s2 = expf(lsv.z), s3 = expf(lsv.w);
    const float a0 = 1.f - s0,   a1 = 1.f - s1,    a2 = 1.f - s2,    a3 = 1.f - s3;

    const float4* xp = x4 + ((size_t)b * T_ + (size_t)chunk * L) * FG + fg;

    float c0 = 0.f, c1 = 0.f, c2 = 0.f, c3 = 0.f;
    #pragma unroll
    for (int i = 0; i < L; ++i) {
        const float4 xv = xp[(size_t)i * FG];
        c0 = fmaf(a0, c0, s0 * xv.x);
        c1 = fmaf(a1, c1, s1 * xv.y);
        c2 = fmaf(a2, c2, s2 * xv.z);
        c3 = fmaf(a3, c3, s3 * xv.w);
    }
    S4[((size_t)b * NC + chunk) * FG + fg] = make_float4(c0, c1, c2, c3);
}

// -------- pass 2: serial combine across chunks, emit per-chunk carries --------
template<int NC>
__global__ __launch_bounds__(32) void pcen_pass2(
    const float4* __restrict__ state4,
    const float*  __restrict__ log_s,
    const float4* __restrict__ S4,
    float4* __restrict__ carry4,
    float4* __restrict__ new_state4)
{
    constexpr int L = T_ / NC;
    const int fg = threadIdx.x;   // 0..31
    const int b  = blockIdx.x;

    const float4 lsv = reinterpret_cast<const float4*>(log_s)[fg];
    const float aL0 = fpow(1.f - expf(lsv.x), (float)L);
    const float aL1 = fpow(1.f - expf(lsv.y), (float)L);
    const float aL2 = fpow(1.f - expf(lsv.z), (float)L);
    const float aL3 = fpow(1.f - expf(lsv.w), (float)L);

    float4 c = state4[(size_t)b * FG + fg];
    #pragma unroll 8
    for (int k = 0; k < NC; ++k) {
        const size_t idx = ((size_t)b * NC + k) * FG + fg;
        carry4[idx] = c;
        const float4 Sv = S4[idx];
        c.x = fmaf(aL0, c.x, Sv.x);
        c.y = fmaf(aL1, c.y, Sv.y);
        c.z = fmaf(aL2, c.z, Sv.z);
        c.w = fmaf(aL3, c.w, Sv.w);
    }
    new_state4[(size_t)b * FG + fg] = c;
}

// -------- pass 3: recurrence from exact carry + y --------
template<int NC>
__global__ __launch_bounds__(256) void pcen_pass3(
    const float4* __restrict__ x4,
    const float*  __restrict__ log_s,
    const float*  __restrict__ log_alpha,
    const float*  __restrict__ log_delta,
    const float*  __restrict__ log_r,
    const float4* __restrict__ carry4,
    float4* __restrict__ y4)
{
    constexpr int L = T_ / NC;
    const int fg    = threadIdx.x & 31;
    const int slot  = threadIdx.x >> 5;
    const int cb    = blockIdx.x % (NC / 8);
    const int b     = blockIdx.x / (NC / 8);
    const int chunk = cb * 8 + slot;

    const float4 lsv = reinterpret_cast<const float4*>(log_s)[fg];
    const float s0 = expf(lsv.x), s1 = expf(lsv.y), s2 = expf(lsv.z), s3 = expf(lsv.w);
    const float a0 = 1.f - s0,   a1 = 1.f - s1,    a2 = 1.f - s2,    a3 = 1.f - s3;

    const float4 lav = reinterpret_cast<const float4*>(log_alpha)[fg];
    const float4 ldv = reinterpret_cast<const float4*>(log_delta)[fg];
    const float4 lrv = reinterpret_cast<const float4*>(log_r)[fg];
    const float na0 = -expf(lav.x), na1 = -expf(lav.y), na2 = -expf(lav.z), na3 = -expf(lav.w);
    const float d0 = expf(ldv.x), d1 = expf(ldv.y), d2 = expf(ldv.z), d3 = expf(ldv.w);
    const float r0 = expf(lrv.x), r1 = expf(lrv.y), r2 = expf(lrv.z), r3 = expf(lrv.w);
    const float dr0 = fpow(d0, r0), dr1 = fpow(d1, r1);
    const float dr2 = fpow(d2, r2), dr3 = fpow(d3, r3);

    float4 c = carry4[((size_t)b * NC + chunk) * FG + fg];

    const size_t base = ((size_t)b * T_ + (size_t)chunk * L) * FG + fg;
    const float4* xp = x4 + base;
    float4*       yp = y4 + base;

    #pragma unroll
    for (int i = 0; i < L; ++i) {
        const float4 xv = xp[(size_t)i * FG];

        c.x = fmaf(a0, c.x, s0 * xv.x);
        c.y = fmaf(a1, c.y, s1 * xv.y);
        c.z = fmaf(a2, c.z, s2 * xv.z);
        c.w = fmaf(a3, c.w, s3 * xv.w);

        // u = x * (EPS+E)^(-alpha);  y = (u + delta)^r - delta^r
        const float u0 = xv.x * exp2f(na0 * __log2f(EPS + c.x));
        const float u1 = xv.y * exp2f(na1 * __log2f(EPS + c.y));
        const float u2 = xv.z * exp2f(na2 * __log2f(EPS + c.z));
        const float u3 = xv.w * exp2f(na3 * __log2f(EPS + c.w));

        float4 yv;
        yv.x = exp2f(r0 * __log2f(u0 + d0)) - dr0;
        yv.y = exp2f(r1 * __log2f(u1 + d1)) - dr1;
        yv.z = exp2f(r2 * __log2f(u2 + d2)) - dr2;
        yv.w = exp2f(r3 * __log2f(u3 + d3)) - dr3;

        yp[(size_t)i * FG] = yv;
    }
}

template<int NC>
static void launch_all(const float* x, const float* state,
                       const float* log_s, const float* log_alpha,
                       const float* log_delta, const float* log_r,
                       float* y, float* new_state, float* ws, hipStream_t stream)
{
    const float4* x4      = (const float4*)x;
    const float4* state4  = (const float4*)state;
    float4* y4            = (float4*)y;
    float4* new_state4    = (float4*)new_state;
    float4* S4            = (float4*)ws;                 // B*NC*FG float4
    float4* carry4        = S4 + (size_t)B_ * NC * FG;   // B*NC*FG float4

    dim3 blk(256);
    dim3 grid(B_ * (NC / 8));

    pcen_pass1<NC><<<grid, blk, 0, stream>>>(x4, log_s, S4);
    pcen_pass2<NC><<<dim3(B_), dim3(32), 0, stream>>>(state4, log_s, S4, carry4, new_state4);
    pcen_pass3<NC><<<grid, blk, 0, stream>>>(x4, log_s, log_alpha, log_delta, log_r, carry4, y4);
}

extern "C" void kernel_launch(void* const* d_in, const int* in_sizes, int n_in,
                              void* d_out, int out_size, void* d_ws, size_t ws_size,
                              hipStream_t stream)
{
    const float* x         = (const float*)d_in[0];
    const float* state     = (const float*)d_in[1];
    const float* log_s     = (const float*)d_in[2];
    const float* log_alpha = (const float*)d_in[3];
    const float* log_delta = (const float*)d_in[4];
    const float* log_r     = (const float*)d_in[5];

    float* y         = (float*)d_out;
    float* new_state = y + (size_t)B_ * T_ * F_;

    // workspace need: 2 buffers of B*NC*F floats
    const size_t need256 = 2ull * B_ * 256 * F_ * sizeof(float);   // 8 MB
    const size_t need128 = 2ull * B_ * 128 * F_ * sizeof(float);   // 4 MB
    if (ws_size >= need256) {
        launch_all<256>(x, state, log_s, log_alpha, log_delta, log_r,
                        y, new_state, (float*)d_ws, stream);
    } else if (ws_size >= need128) {
        launch_all<128>(x, state, log_s, log_alpha, log_delta, log_r,
                        y, new_state, (float*)d_ws, stream);
    } else {
        launch_all<64>(x, state, log_s, log_alpha, log_delta, log_r,
                       y, new_state, (float*)d_ws, stream);
    }
}